// Round 8
// baseline (217.507 us; speedup 1.0000x reference)
//
#include <hip/hip_runtime.h>

#define B_  4
#define C_  256
#define C8_ 32
#define N_  4096   // H*W
#define HVS_ (N_ + 64)  // hv row stride, padded: 8192B power-of-2 stride would alias L1 sets

#define TJ 128     // j-tile per flash block
#define KI 64      // i per iteration
#define SPLITS 4   // i-range splits

typedef __attribute__((ext_vector_type(8)))  short bf16x8;   // MFMA A/B frag (8 bf16)
typedef __attribute__((ext_vector_type(16))) float f32x16;   // MFMA C/D frag

union FragAB { bf16x8 v; unsigned short u[8]; };

__device__ __forceinline__ unsigned short f2bf(float x) {
    unsigned u = __float_as_uint(x);
    unsigned r = u + 0x7FFFu + ((u >> 16) & 1u);   // RNE
    return (unsigned short)(r >> 16);
}
__device__ __forceinline__ unsigned pack2bf(float a, float b) {
    return (unsigned)f2bf(a) | ((unsigned)f2bf(b) << 16);
}
// hw packed f32->bf16 (RNE), 1 instr
__device__ __forceinline__ unsigned cvtpk(float lo, float hi) {
    unsigned r;
    asm("v_cvt_pk_bf16_f32 %0, %1, %2" : "=v"(r) : "v"(lo), "v"(hi));
    return r;
}

// ---------------- prep: W concat -> bf16 [320][256] ----------------
__global__ __launch_bounds__(256) void prep_w_kernel(
    const float* __restrict__ Wq, const float* __restrict__ Wk,
    const float* __restrict__ Wv, unsigned short* __restrict__ Wbf)
{
    int idx = (blockIdx.x * 256 + threadIdx.x) * 4;   // grid 80 -> 81920 elems
    int row = idx >> 8;
    int col = idx & 255;
    const float* src; int r;
    if (row < 32)      { src = Wq; r = row;      }
    else if (row < 64) { src = Wk; r = row - 32; }
    else               { src = Wv; r = row - 64; }
    float4 v = *(const float4*)&src[r * 256 + col];
    uint2 o; o.x = pack2bf(v.x, v.y); o.y = pack2bf(v.z, v.w);
    *(uint2*)&Wbf[idx] = o;
}

// ---------------- fused transpose + MFMA projection --------------------------
// (R7-proven) Also zeroes the flash split-counters (block (0,0)) so the fused
// combine in flash starts clean every graph replay.
__global__ __launch_bounds__(256) void proj_mfma_kernel(
    const float* __restrict__ x, const unsigned short* __restrict__ Wbf,
    unsigned short* __restrict__ fT, unsigned* __restrict__ gdw,
    unsigned short* __restrict__ hv, unsigned* __restrict__ counters)
{
    __shared__ unsigned short T[32][264];   // [n_local][c], row 528B
    int t = threadIdx.x, w = t >> 6, lane = t & 63;
    int half = lane >> 5, l31 = lane & 31;
    int b  = blockIdx.y;
    int n0 = blockIdx.x * 32;

    if (blockIdx.x == 0 && blockIdx.y == 0 && t < B_ * 32)
        counters[t] = 0;   // stream-ordered before flash

    // stage + transpose
    {
        const float* xb = x + (size_t)b * C_ * N_;
        int cr = t >> 3;          // 0..31
        int nc = (t & 7) * 4;     // n chunk base
#pragma unroll
        for (int p = 0; p < 8; ++p) {
            int c = p * 32 + cr;
            float4 v = *(const float4*)&xb[(size_t)c * N_ + n0 + nc];
            T[nc + 0][c] = f2bf(v.x);
            T[nc + 1][c] = f2bf(v.y);
            T[nc + 2][c] = f2bf(v.z);
            T[nc + 3][c] = f2bf(v.w);
        }
    }
    __syncthreads();

    int nm = (w < 2) ? 3 : 2;
    int mt0 = w, mt1 = w + 4, mt2 = w + 8;

    bf16x8 bfr[16];
#pragma unroll
    for (int ks = 0; ks < 16; ++ks)
        bfr[ks] = *(const bf16x8*)&T[l31][ks * 16 + half * 8];

    f32x16 acc[3];
#pragma unroll
    for (int a = 0; a < 3; ++a) acc[a] = (f32x16)0.f;

#pragma unroll
    for (int ks = 0; ks < 16; ++ks) {
        int kofs = ks * 16 + half * 8;
        bf16x8 a0 = *(const bf16x8*)&Wbf[(size_t)(mt0 * 32 + l31) * 256 + kofs];
        acc[0] = __builtin_amdgcn_mfma_f32_32x32x16_bf16(a0, bfr[ks], acc[0], 0, 0, 0);
        bf16x8 a1 = *(const bf16x8*)&Wbf[(size_t)(mt1 * 32 + l31) * 256 + kofs];
        acc[1] = __builtin_amdgcn_mfma_f32_32x32x16_bf16(a1, bfr[ks], acc[1], 0, 0, 0);
        if (nm == 3) {
            bf16x8 a2 = *(const bf16x8*)&Wbf[(size_t)(mt2 * 32 + l31) * 256 + kofs];
            acc[2] = __builtin_amdgcn_mfma_f32_32x32x16_bf16(a2, bfr[ks], acc[2], 0, 0, 0);
        }
    }

    unsigned short* fTb = fT  + (size_t)b * N_ * C8_;
    unsigned*       gb  = gdw + (size_t)b * (C8_ / 2) * N_;
    unsigned short* hb  = hv  + (size_t)b * C_ * HVS_;
#pragma unroll
    for (int im = 0; im < 3; ++im) {
        if (im >= nm) break;
        int mt = (im == 0) ? mt0 : (im == 1) ? mt1 : mt2;
        if (mt == 0) {
#pragma unroll
            for (int rp = 0; rp < 8; ++rp) {
                int r = 2 * rp;
                int R = (r & 3) + 8 * (r >> 2) + 4 * half;
                *(unsigned*)&fTb[(size_t)(n0 + l31) * C8_ + R] = cvtpk(acc[0][r], acc[0][r + 1]);
            }
        } else if (mt == 1) {
#pragma unroll
            for (int rp = 0; rp < 8; ++rp) {
                int r = 2 * rp;
                int R = (r & 3) + 8 * (r >> 2) + 4 * half;   // 0..31, even
                gb[(size_t)(R >> 1) * N_ + n0 + l31] = cvtpk(acc[1][r], acc[1][r + 1]);
            }
        } else {
#pragma unroll
            for (int rp = 0; rp < 8; ++rp) {
                int r = 2 * rp;
                int R = mt * 32 + (r & 3) + 8 * (r >> 2) + 4 * half - 64;
                unsigned u = cvtpk(acc[im][r], acc[im][r + 1]);
                hb[(size_t)R * HVS_ + n0 + l31]       = (unsigned short)(u & 0xffffu);
                hb[(size_t)(R + 1) * HVS_ + n0 + l31] = (unsigned short)(u >> 16);
            }
        }
    }
}

// ---------------- MFMA flash attention + fused combine ------------------------
// Main loop identical to R7 champ. Tail: the 4 split-blocks of each (b,jb)
// column handshake via a device-scope counter (release: threadfence+atomicAdd;
// acquire: threadfence after last-detect). The LAST block re-reads the 4
// partials (L3-hot), normalizes, adds residual, writes out. No spin -> no
// deadlock; counters zeroed by proj, self-cleaned for graph replays.
__global__ __launch_bounds__(256, 2) void flash_kernel(
    const unsigned short* __restrict__ fT, const unsigned* __restrict__ gdw,
    const unsigned short* __restrict__ hv, unsigned* __restrict__ o_part,
    float* __restrict__ l_part, const float* __restrict__ x,
    const float* __restrict__ gamma, float* __restrict__ out,
    unsigned* __restrict__ counters)
{
    __shared__ unsigned short fS[64][40];     // [i][ch]  row 80B (16B aligned)
    __shared__ unsigned short hvT[256][72];   // [c][i]   row 144B
    __shared__ unsigned short pT[128][72];    // [j][i]   row 144B
    __shared__ unsigned oldc;

    int t    = threadIdx.x;
    int w    = t >> 6;
    int lane = t & 63;
    int half = lane >> 5;
    int l31  = lane & 31;

    // XCD grouping: xcd = d&7 hosts pairs {xcd, xcd+8} (verified: FETCH 37->5.7MB)
    int d  = blockIdx.x;
    int jb = (d >> 3) & 31;
    int p  = (d & 7) | (((d >> 8) & 1) << 3);
    int b  = p & 3;
    int s  = p >> 2;
    int j0 = jb * TJ;

    const unsigned short* fb = fT  + (size_t)b * N_ * C8_;
    const unsigned*       gb = gdw + (size_t)b * (C8_ / 2) * N_;
    const unsigned short* hb = hv  + (size_t)b * C_ * HVS_;

    FragAB gf[2];
#pragma unroll
    for (int ks = 0; ks < 2; ++ks)
#pragma unroll
        for (int q = 0; q < 4; ++q) {
            unsigned dv = gb[(size_t)(ks * 8 + half * 4 + q) * N_ + j0 + w * 32 + l31];
            gf[ks].u[2 * q]     = (unsigned short)(dv & 0xffffu);
            gf[ks].u[2 * q + 1] = (unsigned short)(dv >> 16);
        }

    f32x16 acc[8];   // [ct*4 + jt]
#pragma unroll
    for (int a = 0; a < 8; ++a) acc[a] = (f32x16)0.f;
    float lacc = 0.f;

    int i_begin = s * (N_ / SPLITS);
    int i_end   = i_begin + N_ / SPLITS;

    for (int i0 = i_begin; i0 < i_end; i0 += KI) {
        __syncthreads();

        {   // stage fS: [i][ch] 64x32, one uint4 per thread (fT global layout matches)
            int il = t >> 2, c4 = (t & 3) * 8;
            *(uint4*)&fS[il][c4] = *(const uint4*)&fb[(size_t)(i0 + il) * C8_ + c4];
        }
        {   // stage hvT: [c][i], 256 x 64, 8 uint4 per thread
            int crow  = t >> 3;
            int chunk = t & 7;
#pragma unroll
            for (int q = 0; q < 8; ++q) {
                int c = crow + 32 * q;
                *(uint4*)&hvT[c][chunk * 8] =
                    *(const uint4*)&hb[(size_t)c * HVS_ + i0 + chunk * 8];
            }
        }
        __syncthreads();

        // scores + exp -> pT
#pragma unroll
        for (int it = 0; it < 2; ++it) {
            bf16x8 af0 = *(const bf16x8*)&fS[it * 32 + l31][half * 8];
            bf16x8 af1 = *(const bf16x8*)&fS[it * 32 + l31][16 + half * 8];
            f32x16 sacc = (f32x16)0.f;
            sacc = __builtin_amdgcn_mfma_f32_32x32x16_bf16(af0, gf[0].v, sacc, 0, 0, 0);
            sacc = __builtin_amdgcn_mfma_f32_32x32x16_bf16(af1, gf[1].v, sacc, 0, 0, 0);
            float pv[16];
#pragma unroll
            for (int r = 0; r < 16; ++r) pv[r] = __expf(sacc[r]);
            // tree-sum: break the serial fadd chain
            float s0 = (pv[0]  + pv[1])  + (pv[2]  + pv[3]);
            float s1 = (pv[4]  + pv[5])  + (pv[6]  + pv[7]);
            float s2 = (pv[8]  + pv[9])  + (pv[10] + pv[11]);
            float s3 = (pv[12] + pv[13]) + (pv[14] + pv[15]);
            lacc += (s0 + s1) + (s2 + s3);
            int jr = w * 32 + l31;
#pragma unroll
            for (int a = 0; a < 4; ++a) {
                uint2 u;
                u.x = cvtpk(pv[4 * a + 0], pv[4 * a + 1]);
                u.y = cvtpk(pv[4 * a + 2], pv[4 * a + 3]);
                *(uint2*)&pT[jr][it * 32 + 8 * a + 4 * half] = u;
            }
        }
        __syncthreads();

        // PV accumulate
        __builtin_amdgcn_s_setprio(1);
#pragma unroll
        for (int ks4 = 0; ks4 < 4; ++ks4) {
            int kofs = ks4 * 16 + half * 8;
            bf16x8 af[2], bfr[4];
#pragma unroll
            for (int ct = 0; ct < 2; ++ct)
                af[ct] = *(const bf16x8*)&hvT[w * 64 + ct * 32 + l31][kofs];
#pragma unroll
            for (int jt = 0; jt < 4; ++jt)
                bfr[jt] = *(const bf16x8*)&pT[jt * 32 + l31][kofs];
#pragma unroll
            for (int ct = 0; ct < 2; ++ct)
#pragma unroll
                for (int jt = 0; jt < 4; ++jt)
                    acc[ct * 4 + jt] = __builtin_amdgcn_mfma_f32_32x32x16_bf16(
                        af[ct], bfr[jt], acc[ct * 4 + jt], 0, 0, 0);
        }
        __builtin_amdgcn_s_setprio(0);
    }

    // epilogue: o_part c-paired bf16 dwords
    unsigned* ob = o_part + (size_t)(b * SPLITS + s) * (C_ / 2) * N_;
#pragma unroll
    for (int ct = 0; ct < 2; ++ct)
#pragma unroll
        for (int jt = 0; jt < 4; ++jt) {
            f32x16 a = acc[ct * 4 + jt];
#pragma unroll
            for (int rp = 0; rp < 8; ++rp) {
                int r = 2 * rp;
                unsigned u = cvtpk(a[r], a[r + 1]);   // rows c (even), c+1
                int c = w * 64 + ct * 32 + (r & 3) + 8 * (r >> 2) + 4 * half;
                ob[(size_t)(c >> 1) * N_ + j0 + jt * 32 + l31] = u;
            }
        }
    float lsum = lacc + __shfl_down(lacc, 32);
    if (lane < 32)
        l_part[(size_t)(b * SPLITS + s) * N_ + j0 + w * 32 + lane] = lsum;

    // ---- fused combine (last split-block per (b,jb)) ----
    __threadfence();                       // release: o_part/l_part visible device-wide
    __syncthreads();                       // all threads fenced before the atomic
    if (t == 0) oldc = atomicAdd(&counters[b * 32 + jb], 1);
    __syncthreads();
    if (oldc == SPLITS - 1) {
        __threadfence();                   // acquire: other splits' stores visible
        if (t == 0) counters[b * 32 + jb] = 0;   // self-clean for next graph replay
        float gm = gamma[0];
        int jj = t & 127;
        int j  = j0 + jj;
        float l = 0.f;
#pragma unroll
        for (int ss = 0; ss < SPLITS; ++ss)
            l += l_part[(size_t)(b * SPLITS + ss) * N_ + j];
        float inv = 1.f / l;
        int c2base = (t >> 7) * 64;        // threads 0-127: c2 0..63; 128-255: 64..127
        for (int cq = 0; cq < 64; ++cq) {
            int c2 = c2base + cq;
            float olo = 0.f, ohi = 0.f;
#pragma unroll
            for (int ss = 0; ss < SPLITS; ++ss) {
                unsigned u = o_part[((size_t)(b * SPLITS + ss) * (C_ / 2) + c2) * N_ + j];
                olo += __uint_as_float(u << 16);
                ohi += __uint_as_float(u & 0xffff0000u);
            }
            size_t ix = ((size_t)b * C_ + 2 * c2) * N_ + j;
            out[ix]      = gm * olo * inv + x[ix];
            out[ix + N_] = gm * ohi * inv + x[ix + N_];
        }
    }
}

extern "C" void kernel_launch(void* const* d_in, const int* in_sizes, int n_in,
                              void* d_out, int out_size, void* d_ws, size_t ws_size,
                              hipStream_t stream) {
    const float* x     = (const float*)d_in[0];
    const float* Wq    = (const float*)d_in[1];
    const float* Wk    = (const float*)d_in[2];
    const float* Wv    = (const float*)d_in[3];
    const float* gamma = (const float*)d_in[4];
    float* out = (float*)d_out;

    char* ws = (char*)d_ws;
    unsigned* o_part = (unsigned*)ws;                                       // 33.5 MB (c-paired bf16)
    float* l_part = (float*)(o_part + (size_t)SPLITS * B_ * (C_ / 2) * N_); // 256 KB
    unsigned short* fT  = (unsigned short*)(l_part + (size_t)SPLITS * B_ * N_);  // 1 MB
    unsigned*       gdw = (unsigned*)(fT + (size_t)B_ * N_ * C8_);          // 1 MB
    unsigned short* hv  = (unsigned short*)(gdw + (size_t)B_ * (C8_ / 2) * N_);  // 8.5 MB (padded)
    unsigned short* Wbf = hv  + (size_t)B_ * C_ * HVS_;                     // 160 KB
    unsigned* counters  = (unsigned*)(Wbf + (size_t)(C_ + 2 * C8_) * C_);   // 512 B

    prep_w_kernel<<<dim3(80), 256, 0, stream>>>(Wq, Wk, Wv, Wbf);

    proj_mfma_kernel<<<dim3(N_ / 32, B_), 256, 0, stream>>>(x, Wbf, fT, gdw, hv, counters);

    flash_kernel<<<dim3((N_ / TJ) * B_ * SPLITS), 256, 0, stream>>>(
        fT, gdw, hv, o_part, l_part, x, gamma, out, counters);
}

// Round 9
// 146.125 us; speedup vs baseline: 1.4885x; 1.4885x over previous
//
#include <hip/hip_runtime.h>

#define B_  4
#define C_  256
#define C8_ 32
#define N_  4096   // H*W
#define HVS_ (N_ + 64)  // hv row stride, padded: 8192B power-of-2 stride would alias L1 sets

#define TJ 128     // j-tile per flash block
#define KI 64      // i per iteration
#define SPLITS 4   // i-range splits

typedef __attribute__((ext_vector_type(8)))  short bf16x8;   // MFMA A/B frag (8 bf16)
typedef __attribute__((ext_vector_type(16))) float f32x16;   // MFMA C/D frag

union FragAB { bf16x8 v; unsigned short u[8]; };

__device__ __forceinline__ unsigned short f2bf(float x) {
    unsigned u = __float_as_uint(x);
    unsigned r = u + 0x7FFFu + ((u >> 16) & 1u);   // RNE
    return (unsigned short)(r >> 16);
}
// hw packed f32->bf16 (RNE), 1 instr
__device__ __forceinline__ unsigned cvtpk(float lo, float hi) {
    unsigned r;
    asm("v_cvt_pk_bf16_f32 %0, %1, %2" : "=v"(r) : "v"(lo), "v"(hi));
    return r;
}
// load 8 consecutive fp32 -> bf16x8 frag (2 float4 + 4 cvt_pk)
__device__ __forceinline__ bf16x8 ldw8(const float* p) {
    float4 a = *(const float4*)p;
    float4 b = *(const float4*)(p + 4);
    union { bf16x8 v; unsigned u[4]; } r;
    r.u[0] = cvtpk(a.x, a.y);
    r.u[1] = cvtpk(a.z, a.w);
    r.u[2] = cvtpk(b.x, b.y);
    r.u[3] = cvtpk(b.z, b.w);
    return r.v;
}

// ---------------- fused transpose + W-convert + MFMA projection --------------
// prep_x fused (R7-proven): block stages x[b][:][n0..n0+32) fp32 coalesced,
// transposes to bf16 T[n][c] in LDS. prep_w now fused too: A-frags built
// directly from W fp32 rows (1KB-aligned, L2/L3-resident) via 2 float4 + 4
// cvt_pk per frag — removes the prep_w launch (+~10us gap) and Wbf round-trip.
// grid(N/32, B), 256 threads = 4 waves. Wave w: m-tiles {w, w+4, w+8(w<2)}.
__global__ __launch_bounds__(256) void proj_mfma_kernel(
    const float* __restrict__ x, const float* __restrict__ Wq,
    const float* __restrict__ Wk, const float* __restrict__ Wv,
    unsigned short* __restrict__ fT, unsigned* __restrict__ gdw,
    unsigned short* __restrict__ hv)
{
    __shared__ unsigned short T[32][264];   // [n_local][c], row 528B
    int t = threadIdx.x, w = t >> 6, lane = t & 63;
    int half = lane >> 5, l31 = lane & 31;
    int b  = blockIdx.y;
    int n0 = blockIdx.x * 32;

    // stage + transpose
    {
        const float* xb = x + (size_t)b * C_ * N_;
        int cr = t >> 3;          // 0..31
        int nc = (t & 7) * 4;     // n chunk base
#pragma unroll
        for (int p = 0; p < 8; ++p) {
            int c = p * 32 + cr;
            float4 v = *(const float4*)&xb[(size_t)c * N_ + n0 + nc];
            T[nc + 0][c] = f2bf(v.x);
            T[nc + 1][c] = f2bf(v.y);
            T[nc + 2][c] = f2bf(v.z);
            T[nc + 3][c] = f2bf(v.w);
        }
    }
    __syncthreads();

    int nm = (w < 2) ? 3 : 2;
    int mt0 = w, mt1 = w + 4, mt2 = w + 8;

    // W row pointers for this lane's three A-rows (concat row = mt*32 + l31):
    // row<32 -> Wq[row]; 32..63 -> Wk[row-32]; >=64 -> Wv[row-64]
    auto wptr = [&](int R) -> const float* {
        return (R < 32) ? Wq + (size_t)R * 256
             : (R < 64) ? Wk + (size_t)(R - 32) * 256
                        : Wv + (size_t)(R - 64) * 256;
    };
    const float* w0 = wptr(mt0 * 32 + l31);
    const float* w1 = wptr(mt1 * 32 + l31);
    const float* w2 = (nm == 3) ? wptr(mt2 * 32 + l31) : w0;

    bf16x8 bfr[16];
#pragma unroll
    for (int ks = 0; ks < 16; ++ks)
        bfr[ks] = *(const bf16x8*)&T[l31][ks * 16 + half * 8];

    f32x16 acc[3];
#pragma unroll
    for (int a = 0; a < 3; ++a) acc[a] = (f32x16)0.f;

#pragma unroll
    for (int ks = 0; ks < 16; ++ks) {
        int kofs = ks * 16 + half * 8;
        bf16x8 a0 = ldw8(w0 + kofs);
        acc[0] = __builtin_amdgcn_mfma_f32_32x32x16_bf16(a0, bfr[ks], acc[0], 0, 0, 0);
        bf16x8 a1 = ldw8(w1 + kofs);
        acc[1] = __builtin_amdgcn_mfma_f32_32x32x16_bf16(a1, bfr[ks], acc[1], 0, 0, 0);
        if (nm == 3) {
            bf16x8 a2 = ldw8(w2 + kofs);
            acc[2] = __builtin_amdgcn_mfma_f32_32x32x16_bf16(a2, bfr[ks], acc[2], 0, 0, 0);
        }
    }

    unsigned short* fTb = fT  + (size_t)b * N_ * C8_;
    unsigned*       gb  = gdw + (size_t)b * (C8_ / 2) * N_;
    unsigned short* hb  = hv  + (size_t)b * C_ * HVS_;
#pragma unroll
    for (int im = 0; im < 3; ++im) {
        if (im >= nm) break;
        int mt = (im == 0) ? mt0 : (im == 1) ? mt1 : mt2;
        if (mt == 0) {
#pragma unroll
            for (int rp = 0; rp < 8; ++rp) {
                int r = 2 * rp;
                int R = (r & 3) + 8 * (r >> 2) + 4 * half;
                *(unsigned*)&fTb[(size_t)(n0 + l31) * C8_ + R] = cvtpk(acc[0][r], acc[0][r + 1]);
            }
        } else if (mt == 1) {
#pragma unroll
            for (int rp = 0; rp < 8; ++rp) {
                int r = 2 * rp;
                int R = (r & 3) + 8 * (r >> 2) + 4 * half;   // 0..31, even
                gb[(size_t)(R >> 1) * N_ + n0 + l31] = cvtpk(acc[1][r], acc[1][r + 1]);
            }
        } else {
#pragma unroll
            for (int rp = 0; rp < 8; ++rp) {
                int r = 2 * rp;
                int R = mt * 32 + (r & 3) + 8 * (r >> 2) + 4 * half - 64;
                unsigned u = cvtpk(acc[im][r], acc[im][r + 1]);
                hb[(size_t)R * HVS_ + n0 + l31]       = (unsigned short)(u & 0xffffu);
                hb[(size_t)(R + 1) * HVS_ + n0 + l31] = (unsigned short)(u >> 16);
            }
        }
    }
}

// ---------------- MFMA flash attention (exact R7 champion) -------------------
__global__ __launch_bounds__(256, 2) void flash_kernel(
    const unsigned short* __restrict__ fT, const unsigned* __restrict__ gdw,
    const unsigned short* __restrict__ hv, unsigned* __restrict__ o_part,
    float* __restrict__ l_part)
{
    __shared__ unsigned short fS[64][40];     // [i][ch]  row 80B (16B aligned)
    __shared__ unsigned short hvT[256][72];   // [c][i]   row 144B
    __shared__ unsigned short pT[128][72];    // [j][i]   row 144B

    int t    = threadIdx.x;
    int w    = t >> 6;
    int lane = t & 63;
    int half = lane >> 5;
    int l31  = lane & 31;

    // XCD grouping: xcd = d&7 hosts pairs {xcd, xcd+8}; that pair's f/g/hv slice
    // stays resident in one XCD's L2 (verified R1: FETCH 37.4 -> 5.7 MB)
    int d  = blockIdx.x;
    int jb = (d >> 3) & 31;
    int p  = (d & 7) | (((d >> 8) & 1) << 3);
    int b  = p & 3;
    int s  = p >> 2;
    int j0 = jb * TJ;

    const unsigned short* fb = fT  + (size_t)b * N_ * C8_;
    const unsigned*       gb = gdw + (size_t)b * (C8_ / 2) * N_;
    const unsigned short* hb = hv  + (size_t)b * C_ * HVS_;

    FragAB gf[2];
#pragma unroll
    for (int ks = 0; ks < 2; ++ks)
#pragma unroll
        for (int q = 0; q < 4; ++q) {
            unsigned dv = gb[(size_t)(ks * 8 + half * 4 + q) * N_ + j0 + w * 32 + l31];
            gf[ks].u[2 * q]     = (unsigned short)(dv & 0xffffu);
            gf[ks].u[2 * q + 1] = (unsigned short)(dv >> 16);
        }

    f32x16 acc[8];   // [ct*4 + jt]
#pragma unroll
    for (int a = 0; a < 8; ++a) acc[a] = (f32x16)0.f;
    float lacc = 0.f;

    int i_begin = s * (N_ / SPLITS);
    int i_end   = i_begin + N_ / SPLITS;

    for (int i0 = i_begin; i0 < i_end; i0 += KI) {
        __syncthreads();

        {   // stage fS: [i][ch] 64x32, one uint4 per thread (fT global layout matches)
            int il = t >> 2, c4 = (t & 3) * 8;
            *(uint4*)&fS[il][c4] = *(const uint4*)&fb[(size_t)(i0 + il) * C8_ + c4];
        }
        {   // stage hvT: [c][i], 256 x 64, 8 uint4 per thread
            int crow  = t >> 3;
            int chunk = t & 7;
#pragma unroll
            for (int q = 0; q < 8; ++q) {
                int c = crow + 32 * q;
                *(uint4*)&hvT[c][chunk * 8] =
                    *(const uint4*)&hb[(size_t)c * HVS_ + i0 + chunk * 8];
            }
        }
        __syncthreads();

        // scores + exp -> pT
#pragma unroll
        for (int it = 0; it < 2; ++it) {
            bf16x8 af0 = *(const bf16x8*)&fS[it * 32 + l31][half * 8];
            bf16x8 af1 = *(const bf16x8*)&fS[it * 32 + l31][16 + half * 8];
            f32x16 sacc = (f32x16)0.f;
            sacc = __builtin_amdgcn_mfma_f32_32x32x16_bf16(af0, gf[0].v, sacc, 0, 0, 0);
            sacc = __builtin_amdgcn_mfma_f32_32x32x16_bf16(af1, gf[1].v, sacc, 0, 0, 0);
            float pv[16];
#pragma unroll
            for (int r = 0; r < 16; ++r) pv[r] = __expf(sacc[r]);
            // tree-sum: break the serial fadd chain
            float s0 = (pv[0]  + pv[1])  + (pv[2]  + pv[3]);
            float s1 = (pv[4]  + pv[5])  + (pv[6]  + pv[7]);
            float s2 = (pv[8]  + pv[9])  + (pv[10] + pv[11]);
            float s3 = (pv[12] + pv[13]) + (pv[14] + pv[15]);
            lacc += (s0 + s1) + (s2 + s3);
            int jr = w * 32 + l31;
#pragma unroll
            for (int a = 0; a < 4; ++a) {
                uint2 u;
                u.x = cvtpk(pv[4 * a + 0], pv[4 * a + 1]);
                u.y = cvtpk(pv[4 * a + 2], pv[4 * a + 3]);
                *(uint2*)&pT[jr][it * 32 + 8 * a + 4 * half] = u;
            }
        }
        __syncthreads();

        // PV accumulate
        __builtin_amdgcn_s_setprio(1);
#pragma unroll
        for (int ks4 = 0; ks4 < 4; ++ks4) {
            int kofs = ks4 * 16 + half * 8;
            bf16x8 af[2], bfr[4];
#pragma unroll
            for (int ct = 0; ct < 2; ++ct)
                af[ct] = *(const bf16x8*)&hvT[w * 64 + ct * 32 + l31][kofs];
#pragma unroll
            for (int jt = 0; jt < 4; ++jt)
                bfr[jt] = *(const bf16x8*)&pT[jt * 32 + l31][kofs];
#pragma unroll
            for (int ct = 0; ct < 2; ++ct)
#pragma unroll
                for (int jt = 0; jt < 4; ++jt)
                    acc[ct * 4 + jt] = __builtin_amdgcn_mfma_f32_32x32x16_bf16(
                        af[ct], bfr[jt], acc[ct * 4 + jt], 0, 0, 0);
        }
        __builtin_amdgcn_s_setprio(0);
    }

    // epilogue: o_part c-paired bf16 dwords (halves combine traffic)
    unsigned* ob = o_part + (size_t)(b * SPLITS + s) * (C_ / 2) * N_;
#pragma unroll
    for (int ct = 0; ct < 2; ++ct)
#pragma unroll
        for (int jt = 0; jt < 4; ++jt) {
            f32x16 a = acc[ct * 4 + jt];
#pragma unroll
            for (int rp = 0; rp < 8; ++rp) {
                int r = 2 * rp;
                unsigned u = cvtpk(a[r], a[r + 1]);   // rows c (even), c+1
                int c = w * 64 + ct * 32 + (r & 3) + 8 * (r >> 2) + 4 * half;
                ob[(size_t)(c >> 1) * N_ + j0 + jt * 32 + l31] = u;
            }
        }
    float lsum = lacc + __shfl_down(lacc, 32);
    if (lane < 32)
        l_part[(size_t)(b * SPLITS + s) * N_ + j0 + w * 32 + lane] = lsum;
}

// ---------------- combine: sum splits (c-paired bf16), normalize, residual ----
__global__ __launch_bounds__(256) void combine_kernel(
    const unsigned* __restrict__ o_part, const float* __restrict__ l_part,
    const float* __restrict__ x, const float* __restrict__ gamma,
    float* __restrict__ out)
{
    int j = (blockIdx.x * 256 + threadIdx.x) * 4;
    int b = blockIdx.z;
    float4 l4 = {0.f, 0.f, 0.f, 0.f};
#pragma unroll
    for (int s = 0; s < SPLITS; ++s) {
        float4 lv = *(const float4*)&l_part[(size_t)(b * SPLITS + s) * N_ + j];
        l4.x += lv.x; l4.y += lv.y; l4.z += lv.z; l4.w += lv.w;
    }
    float4 inv = {1.f / l4.x, 1.f / l4.y, 1.f / l4.z, 1.f / l4.w};
    float gm = gamma[0];
#pragma unroll
    for (int cc = 0; cc < 2; ++cc) {
        int c2 = blockIdx.y * 2 + cc;            // c-pair: rows 2*c2, 2*c2+1
        float4 olo = {0.f, 0.f, 0.f, 0.f}, ohi = {0.f, 0.f, 0.f, 0.f};
#pragma unroll
        for (int s = 0; s < SPLITS; ++s) {
            uint4 u = *(const uint4*)&o_part[((size_t)(b * SPLITS + s) * (C_ / 2) + c2) * N_ + j];
            olo.x += __uint_as_float(u.x << 16); ohi.x += __uint_as_float(u.x & 0xffff0000u);
            olo.y += __uint_as_float(u.y << 16); ohi.y += __uint_as_float(u.y & 0xffff0000u);
            olo.z += __uint_as_float(u.z << 16); ohi.z += __uint_as_float(u.z & 0xffff0000u);
            olo.w += __uint_as_float(u.w << 16); ohi.w += __uint_as_float(u.w & 0xffff0000u);
        }
        size_t i0 = ((size_t)b * C_ + 2 * c2) * N_ + j;
        float4 x0 = *(const float4*)&x[i0];
        float4 x1 = *(const float4*)&x[i0 + N_];
        float4 r0 = {gm * olo.x * inv.x + x0.x, gm * olo.y * inv.y + x0.y,
                     gm * olo.z * inv.z + x0.z, gm * olo.w * inv.w + x0.w};
        float4 r1 = {gm * ohi.x * inv.x + x1.x, gm * ohi.y * inv.y + x1.y,
                     gm * ohi.z * inv.z + x1.z, gm * ohi.w * inv.w + x1.w};
        *(float4*)&out[i0] = r0;
        *(float4*)&out[i0 + N_] = r1;
    }
}

extern "C" void kernel_launch(void* const* d_in, const int* in_sizes, int n_in,
                              void* d_out, int out_size, void* d_ws, size_t ws_size,
                              hipStream_t stream) {
    const float* x     = (const float*)d_in[0];
    const float* Wq    = (const float*)d_in[1];
    const float* Wk    = (const float*)d_in[2];
    const float* Wv    = (const float*)d_in[3];
    const float* gamma = (const float*)d_in[4];
    float* out = (float*)d_out;

    char* ws = (char*)d_ws;
    unsigned* o_part = (unsigned*)ws;                                       // 33.5 MB (c-paired bf16)
    float* l_part = (float*)(o_part + (size_t)SPLITS * B_ * (C_ / 2) * N_); // 256 KB
    unsigned short* fT  = (unsigned short*)(l_part + (size_t)SPLITS * B_ * N_);  // 1 MB
    unsigned*       gdw = (unsigned*)(fT + (size_t)B_ * N_ * C8_);          // 1 MB
    unsigned short* hv  = (unsigned short*)(gdw + (size_t)B_ * (C8_ / 2) * N_);  // 8.5 MB (padded)

    proj_mfma_kernel<<<dim3(N_ / 32, B_), 256, 0, stream>>>(x, Wq, Wk, Wv, fT, gdw, hv);

    flash_kernel<<<dim3((N_ / TJ) * B_ * SPLITS), 256, 0, stream>>>(fT, gdw, hv, o_part, l_part);

    combine_kernel<<<dim3(N_ / 1024, C_ / 4, B_), 256, 0, stream>>>(o_part, l_part, x, gamma, out);
}

// Round 10
// 138.561 us; speedup vs baseline: 1.5698x; 1.0546x over previous
//
#include <hip/hip_runtime.h>

#define B_  4
#define C_  256
#define C8_ 32
#define N_  4096   // H*W
#define HVS_ (N_ + 64)  // hv row stride, padded: 8192B power-of-2 stride would alias L1 sets

#define TJ 128     // j-tile per flash block
#define KI 64      // i per iteration
#define SPLITS 4   // i-range splits

typedef __attribute__((ext_vector_type(8)))  short bf16x8;   // MFMA A/B frag (8 bf16)
typedef __attribute__((ext_vector_type(16))) float f32x16;   // MFMA C/D frag

union FragAB { bf16x8 v; unsigned short u[8]; };

__device__ __forceinline__ unsigned short f2bf(float x) {
    unsigned u = __float_as_uint(x);
    unsigned r = u + 0x7FFFu + ((u >> 16) & 1u);   // RNE
    return (unsigned short)(r >> 16);
}
__device__ __forceinline__ unsigned pack2bf(float a, float b) {
    return (unsigned)f2bf(a) | ((unsigned)f2bf(b) << 16);
}
// hw packed f32->bf16 (RNE), 1 instr
__device__ __forceinline__ unsigned cvtpk(float lo, float hi) {
    unsigned r;
    asm("v_cvt_pk_bf16_f32 %0, %1, %2" : "=v"(r) : "v"(lo), "v"(hi));
    return r;
}

// ---------------- prep: W concat -> bf16 [320][256] ----------------
__global__ __launch_bounds__(256) void prep_w_kernel(
    const float* __restrict__ Wq, const float* __restrict__ Wk,
    const float* __restrict__ Wv, unsigned short* __restrict__ Wbf)
{
    int idx = (blockIdx.x * 256 + threadIdx.x) * 4;   // grid 80 -> 81920 elems
    int row = idx >> 8;
    int col = idx & 255;
    const float* src; int r;
    if (row < 32)      { src = Wq; r = row;      }
    else if (row < 64) { src = Wk; r = row - 32; }
    else               { src = Wv; r = row - 64; }
    float4 v = *(const float4*)&src[r * 256 + col];
    uint2 o; o.x = pack2bf(v.x, v.y); o.y = pack2bf(v.z, v.w);
    *(uint2*)&Wbf[idx] = o;
}

// ---------------- fused transpose + MFMA projection --------------------------
// prep_x fused: block stages x[b][:][n0..n0+32) fp32 coalesced, transposes to
// bf16 T[n][c] in LDS (row 528B: 33 dwords%32 -> row-dependent banks).
// grid(N/32, B), 256 threads = 4 waves. Wave w: m-tiles {w, w+4, w+8(w<2)}.
__global__ __launch_bounds__(256) void proj_mfma_kernel(
    const float* __restrict__ x, const unsigned short* __restrict__ Wbf,
    unsigned short* __restrict__ fT, unsigned* __restrict__ gdw,
    unsigned short* __restrict__ hv)
{
    __shared__ unsigned short T[32][264];   // [n_local][c], row 528B
    int t = threadIdx.x, w = t >> 6, lane = t & 63;
    int half = lane >> 5, l31 = lane & 31;
    int b  = blockIdx.y;
    int n0 = blockIdx.x * 32;

    // stage + transpose
    {
        const float* xb = x + (size_t)b * C_ * N_;
        int cr = t >> 3;          // 0..31
        int nc = (t & 7) * 4;     // n chunk base
#pragma unroll
        for (int p = 0; p < 8; ++p) {
            int c = p * 32 + cr;
            float4 v = *(const float4*)&xb[(size_t)c * N_ + n0 + nc];
            T[nc + 0][c] = f2bf(v.x);
            T[nc + 1][c] = f2bf(v.y);
            T[nc + 2][c] = f2bf(v.z);
            T[nc + 3][c] = f2bf(v.w);
        }
    }
    __syncthreads();

    int nm = (w < 2) ? 3 : 2;
    int mt0 = w, mt1 = w + 4, mt2 = w + 8;

    bf16x8 bfr[16];
#pragma unroll
    for (int ks = 0; ks < 16; ++ks)
        bfr[ks] = *(const bf16x8*)&T[l31][ks * 16 + half * 8];

    f32x16 acc[3];
#pragma unroll
    for (int a = 0; a < 3; ++a) acc[a] = (f32x16)0.f;

#pragma unroll
    for (int ks = 0; ks < 16; ++ks) {
        int kofs = ks * 16 + half * 8;
        bf16x8 a0 = *(const bf16x8*)&Wbf[(size_t)(mt0 * 32 + l31) * 256 + kofs];
        acc[0] = __builtin_amdgcn_mfma_f32_32x32x16_bf16(a0, bfr[ks], acc[0], 0, 0, 0);
        bf16x8 a1 = *(const bf16x8*)&Wbf[(size_t)(mt1 * 32 + l31) * 256 + kofs];
        acc[1] = __builtin_amdgcn_mfma_f32_32x32x16_bf16(a1, bfr[ks], acc[1], 0, 0, 0);
        if (nm == 3) {
            bf16x8 a2 = *(const bf16x8*)&Wbf[(size_t)(mt2 * 32 + l31) * 256 + kofs];
            acc[2] = __builtin_amdgcn_mfma_f32_32x32x16_bf16(a2, bfr[ks], acc[2], 0, 0, 0);
        }
    }

    unsigned short* fTb = fT  + (size_t)b * N_ * C8_;
    unsigned*       gb  = gdw + (size_t)b * (C8_ / 2) * N_;
    unsigned short* hb  = hv  + (size_t)b * C_ * HVS_;
#pragma unroll
    for (int im = 0; im < 3; ++im) {
        if (im >= nm) break;
        int mt = (im == 0) ? mt0 : (im == 1) ? mt1 : mt2;
        if (mt == 0) {
#pragma unroll
            for (int rp = 0; rp < 8; ++rp) {
                int r = 2 * rp;
                int R = (r & 3) + 8 * (r >> 2) + 4 * half;
                *(unsigned*)&fTb[(size_t)(n0 + l31) * C8_ + R] = cvtpk(acc[0][r], acc[0][r + 1]);
            }
        } else if (mt == 1) {
#pragma unroll
            for (int rp = 0; rp < 8; ++rp) {
                int r = 2 * rp;
                int R = (r & 3) + 8 * (r >> 2) + 4 * half;   // 0..31, even
                gb[(size_t)(R >> 1) * N_ + n0 + l31] = cvtpk(acc[1][r], acc[1][r + 1]);
            }
        } else {
#pragma unroll
            for (int rp = 0; rp < 8; ++rp) {
                int r = 2 * rp;
                int R = mt * 32 + (r & 3) + 8 * (r >> 2) + 4 * half - 64;
                unsigned u = cvtpk(acc[im][r], acc[im][r + 1]);
                hb[(size_t)R * HVS_ + n0 + l31]       = (unsigned short)(u & 0xffffu);
                hb[(size_t)(R + 1) * HVS_ + n0 + l31] = (unsigned short)(u >> 16);
            }
        }
    }
}

// ---------------- MFMA flash attention (R7 champion) -------------------------
__global__ __launch_bounds__(256, 2) void flash_kernel(
    const unsigned short* __restrict__ fT, const unsigned* __restrict__ gdw,
    const unsigned short* __restrict__ hv, unsigned* __restrict__ o_part,
    float* __restrict__ l_part)
{
    __shared__ unsigned short fS[64][40];     // [i][ch]  row 80B (16B aligned)
    __shared__ unsigned short hvT[256][72];   // [c][i]   row 144B
    __shared__ unsigned short pT[128][72];    // [j][i]   row 144B

    int t    = threadIdx.x;
    int w    = t >> 6;
    int lane = t & 63;
    int half = lane >> 5;
    int l31  = lane & 31;

    // XCD grouping: xcd = d&7 hosts pairs {xcd, xcd+8}; that pair's f/g/hv slice
    // stays resident in one XCD's L2 (verified R1: FETCH 37.4 -> 5.7 MB)
    int d  = blockIdx.x;
    int jb = (d >> 3) & 31;
    int p  = (d & 7) | (((d >> 8) & 1) << 3);
    int b  = p & 3;
    int s  = p >> 2;
    int j0 = jb * TJ;

    const unsigned short* fb = fT  + (size_t)b * N_ * C8_;
    const unsigned*       gb = gdw + (size_t)b * (C8_ / 2) * N_;
    const unsigned short* hb = hv  + (size_t)b * C_ * HVS_;

    FragAB gf[2];
#pragma unroll
    for (int ks = 0; ks < 2; ++ks)
#pragma unroll
        for (int q = 0; q < 4; ++q) {
            unsigned dv = gb[(size_t)(ks * 8 + half * 4 + q) * N_ + j0 + w * 32 + l31];
            gf[ks].u[2 * q]     = (unsigned short)(dv & 0xffffu);
            gf[ks].u[2 * q + 1] = (unsigned short)(dv >> 16);
        }

    f32x16 acc[8];   // [ct*4 + jt]
#pragma unroll
    for (int a = 0; a < 8; ++a) acc[a] = (f32x16)0.f;
    float lacc = 0.f;

    int i_begin = s * (N_ / SPLITS);
    int i_end   = i_begin + N_ / SPLITS;

    for (int i0 = i_begin; i0 < i_end; i0 += KI) {
        __syncthreads();

        {   // stage fS: [i][ch] 64x32, one uint4 per thread (fT global layout matches)
            int il = t >> 2, c4 = (t & 3) * 8;
            *(uint4*)&fS[il][c4] = *(const uint4*)&fb[(size_t)(i0 + il) * C8_ + c4];
        }
        {   // stage hvT: [c][i], 256 x 64, 8 uint4 per thread
            int crow  = t >> 3;
            int chunk = t & 7;
#pragma unroll
            for (int q = 0; q < 8; ++q) {
                int c = crow + 32 * q;
                *(uint4*)&hvT[c][chunk * 8] =
                    *(const uint4*)&hb[(size_t)c * HVS_ + i0 + chunk * 8];
            }
        }
        __syncthreads();

        // scores + exp -> pT
#pragma unroll
        for (int it = 0; it < 2; ++it) {
            bf16x8 af0 = *(const bf16x8*)&fS[it * 32 + l31][half * 8];
            bf16x8 af1 = *(const bf16x8*)&fS[it * 32 + l31][16 + half * 8];
            f32x16 sacc = (f32x16)0.f;
            sacc = __builtin_amdgcn_mfma_f32_32x32x16_bf16(af0, gf[0].v, sacc, 0, 0, 0);
            sacc = __builtin_amdgcn_mfma_f32_32x32x16_bf16(af1, gf[1].v, sacc, 0, 0, 0);
            float pv[16];
#pragma unroll
            for (int r = 0; r < 16; ++r) pv[r] = __expf(sacc[r]);
            // tree-sum: break the serial fadd chain
            float s0 = (pv[0]  + pv[1])  + (pv[2]  + pv[3]);
            float s1 = (pv[4]  + pv[5])  + (pv[6]  + pv[7]);
            float s2 = (pv[8]  + pv[9])  + (pv[10] + pv[11]);
            float s3 = (pv[12] + pv[13]) + (pv[14] + pv[15]);
            lacc += (s0 + s1) + (s2 + s3);
            int jr = w * 32 + l31;
#pragma unroll
            for (int a = 0; a < 4; ++a) {
                uint2 u;
                u.x = cvtpk(pv[4 * a + 0], pv[4 * a + 1]);
                u.y = cvtpk(pv[4 * a + 2], pv[4 * a + 3]);
                *(uint2*)&pT[jr][it * 32 + 8 * a + 4 * half] = u;
            }
        }
        __syncthreads();

        // PV accumulate
        __builtin_amdgcn_s_setprio(1);
#pragma unroll
        for (int ks4 = 0; ks4 < 4; ++ks4) {
            int kofs = ks4 * 16 + half * 8;
            bf16x8 af[2], bfr[4];
#pragma unroll
            for (int ct = 0; ct < 2; ++ct)
                af[ct] = *(const bf16x8*)&hvT[w * 64 + ct * 32 + l31][kofs];
#pragma unroll
            for (int jt = 0; jt < 4; ++jt)
                bfr[jt] = *(const bf16x8*)&pT[jt * 32 + l31][kofs];
#pragma unroll
            for (int ct = 0; ct < 2; ++ct)
#pragma unroll
                for (int jt = 0; jt < 4; ++jt)
                    acc[ct * 4 + jt] = __builtin_amdgcn_mfma_f32_32x32x16_bf16(
                        af[ct], bfr[jt], acc[ct * 4 + jt], 0, 0, 0);
        }
        __builtin_amdgcn_s_setprio(0);
    }

    // epilogue: o_part c-paired bf16 dwords (halves combine traffic)
    unsigned* ob = o_part + (size_t)(b * SPLITS + s) * (C_ / 2) * N_;
#pragma unroll
    for (int ct = 0; ct < 2; ++ct)
#pragma unroll
        for (int jt = 0; jt < 4; ++jt) {
            f32x16 a = acc[ct * 4 + jt];
#pragma unroll
            for (int rp = 0; rp < 8; ++rp) {
                int r = 2 * rp;
                unsigned u = cvtpk(a[r], a[r + 1]);   // rows c (even), c+1
                int c = w * 64 + ct * 32 + (r & 3) + 8 * (r >> 2) + 4 * half;
                ob[(size_t)(c >> 1) * N_ + j0 + jt * 32 + l31] = u;
            }
        }
    float lsum = lacc + __shfl_down(lacc, 32);
    if (lane < 32)
        l_part[(size_t)(b * SPLITS + s) * N_ + j0 + w * 32 + lane] = lsum;
}

// ---------------- combine: sum splits (c-paired bf16), normalize, residual ----
__global__ __launch_bounds__(256) void combine_kernel(
    const unsigned* __restrict__ o_part, const float* __restrict__ l_part,
    const float* __restrict__ x, const float* __restrict__ gamma,
    float* __restrict__ out)
{
    int j = (blockIdx.x * 256 + threadIdx.x) * 4;
    int b = blockIdx.z;
    float4 l4 = {0.f, 0.f, 0.f, 0.f};
#pragma unroll
    for (int s = 0; s < SPLITS; ++s) {
        float4 lv = *(const float4*)&l_part[(size_t)(b * SPLITS + s) * N_ + j];
        l4.x += lv.x; l4.y += lv.y; l4.z += lv.z; l4.w += lv.w;
    }
    float4 inv = {1.f / l4.x, 1.f / l4.y, 1.f / l4.z, 1.f / l4.w};
    float gm = gamma[0];
#pragma unroll
    for (int cc = 0; cc < 2; ++cc) {
        int c2 = blockIdx.y * 2 + cc;            // c-pair: rows 2*c2, 2*c2+1
        float4 olo = {0.f, 0.f, 0.f, 0.f}, ohi = {0.f, 0.f, 0.f, 0.f};
#pragma unroll
        for (int s = 0; s < SPLITS; ++s) {
            uint4 u = *(const uint4*)&o_part[((size_t)(b * SPLITS + s) * (C_ / 2) + c2) * N_ + j];
            olo.x += __uint_as_float(u.x << 16); ohi.x += __uint_as_float(u.x & 0xffff0000u);
            olo.y += __uint_as_float(u.y << 16); ohi.y += __uint_as_float(u.y & 0xffff0000u);
            olo.z += __uint_as_float(u.z << 16); ohi.z += __uint_as_float(u.z & 0xffff0000u);
            olo.w += __uint_as_float(u.w << 16); ohi.w += __uint_as_float(u.w & 0xffff0000u);
        }
        size_t i0 = ((size_t)b * C_ + 2 * c2) * N_ + j;
        float4 x0 = *(const float4*)&x[i0];
        float4 x1 = *(const float4*)&x[i0 + N_];
        float4 r0 = {gm * olo.x * inv.x + x0.x, gm * olo.y * inv.y + x0.y,
                     gm * olo.z * inv.z + x0.z, gm * olo.w * inv.w + x0.w};
        float4 r1 = {gm * ohi.x * inv.x + x1.x, gm * ohi.y * inv.y + x1.y,
                     gm * ohi.z * inv.z + x1.z, gm * ohi.w * inv.w + x1.w};
        *(float4*)&out[i0] = r0;
        *(float4*)&out[i0 + N_] = r1;
    }
}

extern "C" void kernel_launch(void* const* d_in, const int* in_sizes, int n_in,
                              void* d_out, int out_size, void* d_ws, size_t ws_size,
                              hipStream_t stream) {
    const float* x     = (const float*)d_in[0];
    const float* Wq    = (const float*)d_in[1];
    const float* Wk    = (const float*)d_in[2];
    const float* Wv    = (const float*)d_in[3];
    const float* gamma = (const float*)d_in[4];
    float* out = (float*)d_out;

    char* ws = (char*)d_ws;
    unsigned* o_part = (unsigned*)ws;                                       // 33.5 MB (c-paired bf16)
    float* l_part = (float*)(o_part + (size_t)SPLITS * B_ * (C_ / 2) * N_); // 256 KB
    unsigned short* fT  = (unsigned short*)(l_part + (size_t)SPLITS * B_ * N_);  // 1 MB
    unsigned*       gdw = (unsigned*)(fT + (size_t)B_ * N_ * C8_);          // 1 MB
    unsigned short* hv  = (unsigned short*)(gdw + (size_t)B_ * (C8_ / 2) * N_);  // 8.5 MB (padded)
    unsigned short* Wbf = hv  + (size_t)B_ * C_ * HVS_;                     // 160 KB

    prep_w_kernel<<<dim3(80), 256, 0, stream>>>(Wq, Wk, Wv, Wbf);

    proj_mfma_kernel<<<dim3(N_ / 32, B_), 256, 0, stream>>>(x, Wbf, fT, gdw, hv);

    flash_kernel<<<dim3((N_ / TJ) * B_ * SPLITS), 256, 0, stream>>>(fT, gdw, hv, o_part, l_part);

    combine_kernel<<<dim3(N_ / 1024, C_ / 4, B_), 256, 0, stream>>>(o_part, l_part, x, gamma, out);
}